// Round 7
// baseline (165.655 us; speedup 1.0000x reference)
//
#include <hip/hip_runtime.h>
#include <math.h>

#define NVIEW 8
#define CIN   32
#define HF    128
#define WF    128
#define C1    32
#define C2    16
#define C3    8
#define RESO  64
#define PLANE (HF*WF)          // 16384 texels; Gh interleaved: 4 uint4 (32ch) per texel

typedef _Float16 half8_t  __attribute__((ext_vector_type(8)));
typedef _Float16 half2_t  __attribute__((ext_vector_type(2)));
typedef float    floatx4  __attribute__((ext_vector_type(4)));

static __device__ __forceinline__ float vox_coord(int idx, float b) {
    const float VOXEL = (float)(0.3 / 64.0);
    const float HALFV = (float)(0.3 / 128.0);
    return (float)idx * VOXEL + HALFV + b;
}

// wave-level LDS sync: each wave uses a private LDS slice; DS ops are in-order
// per wave, so only a lgkmcnt drain + compiler barrier is needed. No s_barrier.
// Global loads count against vmcnt, so loads issued BEFORE this in source
// order stay in flight across it (the prefetch mechanism below).
static __device__ __forceinline__ void wave_lds_sync() {
    asm volatile("s_waitcnt lgkmcnt(0)" ::: "memory");
}

// ---- K1: G in fp16, INTERLEAVED layout: Gh[(v*PLANE + pix)*4 + grp] -> one
// 64 B cache line holds all 32 channels of a texel. Each thread owns one
// texel, computes all 32 layer-1 outputs (per-output FMA order over c
// unchanged -> bit-identical). Block 512 preps mats / fp16 weight frags. ----
__global__ void __launch_bounds__(256) k_g(const float* __restrict__ feats,
                                           const float* __restrict__ W1,
                                           const float* __restrict__ b1,
                                           uint4* __restrict__ Gh,
                                           const float* __restrict__ Ks,
                                           const float* __restrict__ poses,
                                           const int* __restrict__ ihp,
                                           const int* __restrict__ iwp,
                                           const float* __restrict__ W2,
                                           const float* __restrict__ b2,
                                           const float* __restrict__ W3,
                                           const float* __restrict__ b3,
                                           float* __restrict__ mats,
                                           _Float16* __restrict__ w2f,
                                           _Float16* __restrict__ w3f,
                                           float* __restrict__ b2f,
                                           float* __restrict__ b3f) {
    if (blockIdx.x == 512) {
        int t = threadIdx.x;
        if (t < NVIEW * 12) {
            int v = t / 12, rc = t % 12, r = rc / 4, c = rc % 4;
            const float* K = Ks + v * 9;
            const float* P = poses + v * 12;
            float s = K[r*3+0]*P[0*4+c] + K[r*3+1]*P[1*4+c] + K[r*3+2]*P[2*4+c];
            float sc = (r == 0) ? 63.5f / (float)iwp[0]
                     : (r == 1) ? 63.5f / (float)ihp[0] : 1.0f;
            mats[v*12 + r*4 + c] = s * sc;
        }
        if (t < 64) {
            int n = t & 15, g = t >> 4;
            // frag for mfma_f32_16x16x32_f16: lane holds X[k=8g+j][n], j=0..7
            // (works as B-frag, and as A-frag of the transposed matrix)
#pragma unroll
            for (int jj = 0; jj < 8; jj++) {
                int kk = 8 * g + jj;
                w2f[t*8 + jj] = (_Float16)W2[kk * C2 + n];
                float w3v = (kk < C2 && n < C3) ? W3[kk * C3 + n] : 0.0f;  // K,N zero-pad
                w3f[t*8 + jj] = (_Float16)w3v;
            }
            b2f[t] = b2[n];
            b3f[t] = (n < C3) ? b3[n] : 0.0f;
        }
        return;
    }
    // 512 blocks: [view(8)][pixblk(64)] ; thread = one texel, all 32 outputs
    int bx = blockIdx.x;
    int pix = (bx & 63) * 256 + threadIdx.x;   // coalesced
    int v   = bx >> 6;
    const float* fp = feats + ((size_t)v * CIN) * PLANE + pix;
    float g[32];
#pragma unroll
    for (int o = 0; o < C1; o++) g[o] = b1[o];
#pragma unroll
    for (int cc = 0; cc < CIN; cc += 8) {
        float fc[8];
#pragma unroll
        for (int q = 0; q < 8; q++) fc[q] = fp[(size_t)(cc + q) * PLANE];
#pragma unroll
        for (int q = 0; q < 8; q++) {
#pragma unroll
            for (int o = 0; o < C1; o++)
                g[o] = fmaf(fc[q], W1[(cc + q) * C1 + o], g[o]);
        }
    }
    uint4* gp = Gh + ((size_t)v * PLANE + pix) * 4;
#pragma unroll
    for (int grp = 0; grp < 4; grp++) {
        union { half2_t h2[4]; uint4 u; } pk;
#pragma unroll
        for (int q = 0; q < 4; q++) {
            half2_t p = { (_Float16)g[grp*8 + 2*q], (_Float16)g[grp*8 + 2*q + 1] };   // RTNE
            pk.h2[q] = p;
        }
        gp[grp] = pk.u;
    }
}

// ---- K2: wave = one 64-voxel column, LANE = POINT (R6 structure) plus:
// (a) layer-3 operand swap: c3' = mfma(w3frag, a3, cb3p) computes C3^T.
//     Same h2 ds_read works as B-frag (value h2[pt][ch] serves both roles);
//     same w3f works as A-frag (= W3^T with zero-padded rows/k). Products and
//     k-order unchanged -> bit-identical. New C layout: lane (m,g) holds
//     (pt=T*16+m, ch=g*4+r) -> mask weight w once per TILE, S 16->4 regs:
//     accumulators 48->36 VGPR.
// (b) T14 async-split prefetch: view v+1's A,B corner loads issue after the
//     h2 writes (before sync2) -> in flight across sync2+layer-3; C,D load
//     at view start hides under the A,B blend. Partial projection recompute
//     (~25 VALU) instead of carrying proj state. 4 waves/SIMD kept. ----
__global__ void __launch_bounds__(256, 4) k_main(
    const uint4* __restrict__ Gh,
    const float* __restrict__ mats, const float* __restrict__ bbox,
    const _Float16* __restrict__ w2f, const _Float16* __restrict__ w3f,
    const float* __restrict__ b2f, const float* __restrict__ b3f,
    float* __restrict__ out) {
#pragma clang fp contract(fast)
    __shared__ __align__(16) _Float16 a2s[4][64 * 32];   // per-wave A-stage (4 KB)
    __shared__ __align__(16) _Float16 h2s[4][64 * 24];   // per-wave h2 slice (3 KB)

    int tid  = threadIdx.x;
    int wv   = tid >> 6;
    int lane = tid & 63;
    int bxs  = (blockIdx.x & 7) * 128 + (blockIdx.x >> 3);  // XCD swizzle (bijective)
    int col  = bxs * 4 + wv;               // 4096 columns: (k<<6)|j
    int j  = col & 63;
    int kz = col >> 6;
    _Float16* a2b = a2s[wv];
    _Float16* h2b = h2s[wv];

    int m = lane & 15, g = lane >> 4;
    float y = vox_coord(j, bbox[1]);
    float z = vox_coord(kz, bbox[2]);
    float x = vox_coord(lane, bbox[0]);    // lane = point index in column

    half8_t w2frag = *(const half8_t*)(w2f + lane * 8);
    half8_t w3frag = *(const half8_t*)(w3f + lane * 8);
    float b2c = b2f[lane];
    floatx4 cb2 = {b2c, b2c, b2c, b2c};
    floatx4 cb3p = { b3f[g*4+0], b3f[g*4+1], b3f[g*4+2], b3f[g*4+3] };  // per-row bias
    const half2_t z2 = { (_Float16)0.0f, (_Float16)0.0f };

    // A-stage slot offsets (halves): write lane p block q -> p*32 + (q^((p>>1)&3))*8
    int wsw0 = (lane >> 1) & 3;            // write-side swizzle key
    int rsw0 = (m >> 1) & 3;               // read-side swizzle key (same key, p=T*16+m)

    float M1[16], Msq[16], S4[4];
#pragma unroll
    for (int c = 0; c < 16; c++) { M1[c] = 0.0f; Msq[c] = 0.0f; }
#pragma unroll
    for (int c = 0; c < 4; c++) S4[c] = 0.0f;

    union UAB { uint4 u[8]; half2_t h[32]; } ab;   // prefetched A,B corners (loop-carried)
    union UCD { uint4 u[8]; half2_t h[32]; } cd;   // C,D corners (transient)

    // partial projection of view VV -> issue A,B corner-line loads into AB
#define ISSUE_AB(VV, AB) do {                                            \
        const float* M_ = mats + (VV) * 12;                              \
        const uint4* Gp_ = Gh + (size_t)(VV) * (PLANE * 4);              \
        float Ku_ = fmaf(M_[1], y, fmaf(M_[2],  z, M_[3]));              \
        float Kv_ = fmaf(M_[5], y, fmaf(M_[6],  z, M_[7]));              \
        float Kz_ = fmaf(M_[9], y, fmaf(M_[10], z, M_[11]));             \
        float u_  = fmaf(M_[0], x, Ku_);                                 \
        float vv_ = fmaf(M_[4], x, Kv_);                                 \
        float zc_ = fmaf(M_[8], x, Kz_);                                 \
        float invz_ = __builtin_amdgcn_rcpf(zc_);                        \
        float ix_ = u_ * invz_, iy_ = vv_ * invz_;                       \
        float fx0_ = floorf(ix_), fy0_ = floorf(iy_);                    \
        int cx0_ = (int)fminf(fmaxf(fx0_, 0.0f), (float)(WF-1));         \
        int cx1_ = (int)fminf(fmaxf(fx0_ + 1.0f, 0.0f), (float)(WF-1)); \
        int cy0_ = (int)fminf(fmaxf(fy0_, 0.0f), (float)(HF-1));         \
        const uint4* pA_ = Gp_ + (size_t)(cy0_ * WF + cx0_) * 4;         \
        const uint4* pB_ = Gp_ + (size_t)(cy0_ * WF + cx1_) * 4;         \
        AB.u[0] = pA_[0]; AB.u[1] = pA_[1]; AB.u[2] = pA_[2]; AB.u[3] = pA_[3]; \
        AB.u[4] = pB_[0]; AB.u[5] = pB_[1]; AB.u[6] = pB_[2]; AB.u[7] = pB_[3]; \
    } while (0)

    ISSUE_AB(0, ab);   // prologue: view 0's A,B in flight

#pragma unroll 1
    for (int v = 0; v < NVIEW; v++) {
        const float* M = mats + v * 12;
        const uint4* Gp = Gh + (size_t)v * (PLANE * 4);

        // full projection (same association as reference -> bit-identical)
        float Ku = fmaf(M[1], y, fmaf(M[2],  z, M[3]));
        float Kv = fmaf(M[5], y, fmaf(M[6],  z, M[7]));
        float Kz = fmaf(M[9], y, fmaf(M[10], z, M[11]));
        float u  = fmaf(M[0], x, Ku);
        float vv = fmaf(M[4], x, Kv);
        float zc = fmaf(M[8], x, Kz);
        float invz = __builtin_amdgcn_rcpf(zc);
        float ix = u * invz;
        float iy = vv * invz;

        float fx0 = floorf(ix), fy0 = floorf(iy);
        float fx1 = fx0 + 1.0f, fy1 = fy0 + 1.0f;
        bool inb = (ix >= 0.0f) && (ix <= (float)(WF-1)) &&
                   (iy >= 0.0f) && (iy <= (float)(HF-1)) && (zc > 0.0f);
        int cx0 = (int)fminf(fmaxf(fx0, 0.0f), (float)(WF-1));
        int cx1 = (int)fminf(fmaxf(fx1, 0.0f), (float)(WF-1));
        int cy1 = (int)fminf(fmaxf(fy1, 0.0f), (float)(HF-1));
        float wnw = (fx1 - ix) * (fy1 - iy);
        float wne = (ix - fx0) * (fy1 - iy);
        float wsw = (fx1 - ix) * (iy - fy0);
        float wse = (ix - fx0) * (iy - fy0);

        unsigned long long bal = __ballot(inb);    // bit p = point p in-bounds

        // C,D corner loads (latency hidden under A,B blend below)
        const uint4* pC = Gp + (size_t)(cy1 * WF + cx0) * 4;
        const uint4* pD = Gp + (size_t)(cy1 * WF + cx1) * 4;
#pragma unroll
        for (int q = 0; q < 4; q++) cd.u[q]     = pC[q];
#pragma unroll
        for (int q = 0; q < 4; q++) cd.u[4 + q] = pD[q];

        half2_t wnw2 = { (_Float16)wnw, (_Float16)wnw };   // RTNE, once per view
        half2_t wne2 = { (_Float16)wne, (_Float16)wne };
        half2_t wsw2 = { (_Float16)wsw, (_Float16)wsw };
        half2_t wse2 = { (_Float16)wse, (_Float16)wse };

        // blend all 32 channels; per-channel op order identical to R6:
        // ((A*wnw) + B*wne) + C*wsw) + D*wse, relu -> bit-identical.
        union { uint4 u[4]; half2_t h[16]; } acc;
#pragma unroll
        for (int c = 0; c < 16; c++) acc.h[c] = ab.h[c] * wnw2;
#pragma unroll
        for (int c = 0; c < 16; c++) acc.h[c] = ab.h[16 + c] * wne2 + acc.h[c];
#pragma unroll
        for (int c = 0; c < 16; c++) acc.h[c] = cd.h[c] * wsw2 + acc.h[c];
#pragma unroll
        for (int c = 0; c < 16; c++) {
            acc.h[c] = cd.h[16 + c] * wse2 + acc.h[c];
            acc.h[c] = __builtin_elementwise_max(acc.h[c], z2);   // relu, packed
        }

        // stage A-frags (swizzled, conflict-free); WAR vs prev view's reads is
        // safe: DS ops are in-order per wave.
#pragma unroll
        for (int q = 0; q < 4; q++)
            *(uint4*)(a2b + lane * 32 + (q ^ wsw0) * 8) = acc.u[q];
        wave_lds_sync();

        // layer 2 per tile: read A-frag, MFMA, relu+cvt into h2 [pt][ch]
#pragma unroll
        for (int T = 0; T < 4; T++) {
            half8_t a2 = *(const half8_t*)(a2b + (T*16 + m) * 32 + (g ^ rsw0) * 8);
            floatx4 c2 = __builtin_amdgcn_mfma_f32_16x16x32_f16(a2, w2frag, cb2, 0, 0, 0);
#pragma unroll
            for (int r = 0; r < 4; r++) {
                float hv = fmaxf(c2[r], 0.0f);
                h2b[(T*16 + g*4 + r) * 24 + m] = (_Float16)hv;
            }
        }

        // prefetch next view's A,B BEFORE sync2 -> in flight across layer 3
        if (v < NVIEW - 1) ISSUE_AB(v + 1, ab);
        wave_lds_sync();

        // layer 3 (operand-swapped): c3' = W3^T-as-A x h2-as-B + bias.
        // C^T layout: lane (m,g) reg r -> (pt = T*16+m, out-ch = g*4+r).
        float msr = __builtin_amdgcn_rcpf((float)__popcll(bal) + 1e-8f);
        unsigned int balT[4];
        balT[0] = (unsigned int)bal;
        balT[1] = (unsigned int)(bal >> 16);
        balT[2] = (unsigned int)(bal >> 32);
        balT[3] = (unsigned int)(bal >> 48);
#pragma unroll
        for (int T = 0; T < 4; T++) {
            half8_t a3 = *(const half8_t*)(h2b + (T*16 + m) * 24 + (g & 1) * 8);
            floatx4 c3 = __builtin_amdgcn_mfma_f32_16x16x32_f16(w3frag, a3, cb3p, 0, 0, 0);
            float w = ((balT[T] >> m) & 1u) ? msr : 0.0f;   // my point, once per tile
            S4[T] += w;
#pragma unroll
            for (int r = 0; r < 4; r++) {
                float val = c3[r];
                float t1 = w * val;
                M1[T*4+r]  += t1;
                Msq[T*4+r]  = fmaf(t1, val, Msq[T*4+r]);
            }
        }
    }
#undef ISSUE_AB

    // epilogue: lane (m, g<2) owns pts T*16+m, out-chs g*4+r.
    // mean plane ch, var plane ch+8; lanes m=0..15 write 64 B bursts.
    if (g < 2) {
        size_t base = (size_t)col * 64;
#pragma unroll
        for (int T = 0; T < 4; T++) {
#pragma unroll
            for (int r = 0; r < 4; r++) {
                float mn = M1[T*4+r];
                float vr = fmaf(mn*mn, S4[T] - 2.0f, Msq[T*4+r]);
                size_t ob = base + T*16 + m;
                out[(size_t)(g*4 + r)     * 262144 + ob] = mn;
                out[(size_t)(g*4 + r + 8) * 262144 + ob] = vr;
            }
        }
    }
}

// ---- launch ----
extern "C" void kernel_launch(void* const* d_in, const int* in_sizes, int n_in,
                              void* d_out, int out_size, void* d_ws, size_t ws_size,
                              hipStream_t stream) {
    const float* feats = (const float*)d_in[0];
    const float* poses = (const float*)d_in[1];
    const float* Ks    = (const float*)d_in[2];
    const float* bbox  = (const float*)d_in[3];
    const int*   img_h = (const int*)d_in[4];
    const int*   img_w = (const int*)d_in[5];
    const float* W1    = (const float*)d_in[6];
    const float* b1    = (const float*)d_in[7];
    const float* W2    = (const float*)d_in[8];
    const float* b2    = (const float*)d_in[9];
    const float* W3    = (const float*)d_in[10];
    const float* b3    = (const float*)d_in[11];
    float* out = (float*)d_out;
    float* ws  = (float*)d_ws;

    float*     mats = ws;                        // 96 floats (pad to 128)
    _Float16*  w2f  = (_Float16*)(ws + 128);     // 512 halves (256 floats)
    _Float16*  w3f  = (_Float16*)(ws + 384);     // 512 halves
    float*     b2f  = ws + 640;                  // 64
    float*     b3f  = ws + 704;                  // 64
    uint4*     Gh   = (uint4*)(ws + 768);        // 8*16384*64 B = 8.39 MB, 16B-aligned

    hipLaunchKernelGGL(k_g, dim3(513), dim3(256), 0, stream,
                       feats, W1, b1, Gh, Ks, poses, img_h, img_w,
                       W2, b2, W3, b3, mats, w2f, w3f, b2f, b3f);
    hipLaunchKernelGGL(k_main, dim3(1024), dim3(256), 0, stream,
                       Gh, mats, bbox, w2f, w3f, b2f, b3f, out);
}

// Round 8
// 124.267 us; speedup vs baseline: 1.3331x; 1.3331x over previous
//
#include <hip/hip_runtime.h>
#include <math.h>

#define NVIEW 8
#define CIN   32
#define HF    128
#define WF    128
#define C1    32
#define C2    16
#define C3    8
#define RESO  64
#define PLANE (HF*WF)          // 16384 texels; Gh interleaved: 4 uint4 (32ch) per texel

typedef _Float16 half8_t  __attribute__((ext_vector_type(8)));
typedef _Float16 half2_t  __attribute__((ext_vector_type(2)));
typedef float    floatx4  __attribute__((ext_vector_type(4)));

static __device__ __forceinline__ float vox_coord(int idx, float b) {
    const float VOXEL = (float)(0.3 / 64.0);
    const float HALFV = (float)(0.3 / 128.0);
    return (float)idx * VOXEL + HALFV + b;
}

// wave-level LDS sync: each wave uses a private LDS slice; DS ops are in-order
// per wave, so only a lgkmcnt drain + compiler barrier is needed. No s_barrier.
static __device__ __forceinline__ void wave_lds_sync() {
    asm volatile("s_waitcnt lgkmcnt(0)" ::: "memory");
}

// ---- K1: G in fp16, INTERLEAVED layout: Gh[(v*PLANE + pix)*4 + grp] -> one
// 64 B cache line holds all 32 channels of a texel. Each thread owns one
// texel, computes all 32 layer-1 outputs (per-output FMA order over c
// unchanged -> bit-identical). Block 512 preps mats / fp16 weight frags. ----
__global__ void __launch_bounds__(256) k_g(const float* __restrict__ feats,
                                           const float* __restrict__ W1,
                                           const float* __restrict__ b1,
                                           uint4* __restrict__ Gh,
                                           const float* __restrict__ Ks,
                                           const float* __restrict__ poses,
                                           const int* __restrict__ ihp,
                                           const int* __restrict__ iwp,
                                           const float* __restrict__ W2,
                                           const float* __restrict__ b2,
                                           const float* __restrict__ W3,
                                           const float* __restrict__ b3,
                                           float* __restrict__ mats,
                                           _Float16* __restrict__ w2f,
                                           _Float16* __restrict__ w3f,
                                           float* __restrict__ b2f,
                                           float* __restrict__ b3f) {
    if (blockIdx.x == 512) {
        int t = threadIdx.x;
        if (t < NVIEW * 12) {
            int v = t / 12, rc = t % 12, r = rc / 4, c = rc % 4;
            const float* K = Ks + v * 9;
            const float* P = poses + v * 12;
            float s = K[r*3+0]*P[0*4+c] + K[r*3+1]*P[1*4+c] + K[r*3+2]*P[2*4+c];
            float sc = (r == 0) ? 63.5f / (float)iwp[0]
                     : (r == 1) ? 63.5f / (float)ihp[0] : 1.0f;
            mats[v*12 + r*4 + c] = s * sc;
        }
        if (t < 64) {
            int n = t & 15, g = t >> 4;
            // frag for mfma_f32_16x16x32_f16: lane holds X[k=8g+j][n], j=0..7
            // (works as B-frag, and as A-frag of the transposed matrix)
#pragma unroll
            for (int jj = 0; jj < 8; jj++) {
                int kk = 8 * g + jj;
                w2f[t*8 + jj] = (_Float16)W2[kk * C2 + n];
                float w3v = (kk < C2 && n < C3) ? W3[kk * C3 + n] : 0.0f;  // K,N zero-pad
                w3f[t*8 + jj] = (_Float16)w3v;
            }
            b2f[t] = b2[n];
            b3f[t] = (n < C3) ? b3[n] : 0.0f;
        }
        return;
    }
    // 512 blocks: [view(8)][pixblk(64)] ; thread = one texel, all 32 outputs
    int bx = blockIdx.x;
    int pix = (bx & 63) * 256 + threadIdx.x;   // coalesced
    int v   = bx >> 6;
    const float* fp = feats + ((size_t)v * CIN) * PLANE + pix;
    float g[32];
#pragma unroll
    for (int o = 0; o < C1; o++) g[o] = b1[o];
#pragma unroll
    for (int cc = 0; cc < CIN; cc += 8) {
        float fc[8];
#pragma unroll
        for (int q = 0; q < 8; q++) fc[q] = fp[(size_t)(cc + q) * PLANE];
#pragma unroll
        for (int q = 0; q < 8; q++) {
#pragma unroll
            for (int o = 0; o < C1; o++)
                g[o] = fmaf(fc[q], W1[(cc + q) * C1 + o], g[o]);
        }
    }
    uint4* gp = Gh + ((size_t)v * PLANE + pix) * 4;
#pragma unroll
    for (int grp = 0; grp < 4; grp++) {
        union { half2_t h2[4]; uint4 u; } pk;
#pragma unroll
        for (int q = 0; q < 4; q++) {
            half2_t p = { (_Float16)g[grp*8 + 2*q], (_Float16)g[grp*8 + 2*q + 1] };   // RTNE
            pk.h2[q] = p;
        }
        gp[grp] = pk.u;
    }
}

// ---- K2: wave = one 64-voxel column, LANE = POINT (R6 structure, consume-
// in-place: R2/R5/R7 all proved loop-carried gather state spills). Deltas:
// (a) layer-3 operand swap (proven bit-identical in R7): c3' =
//     mfma(w3frag, a3, cb3p) computes C3^T; lane (m,g) reg r holds
//     (pt=T*16+m, ch=g*4+r) -> mask weight once per TILE, S 16->4 regs.
// (b) view loop unroll 2 (R4's setting): compiler-managed interleave of two
//     independent view chains within the 128-reg cap; no held state. ----
__global__ void __launch_bounds__(256, 4) k_main(
    const uint4* __restrict__ Gh,
    const float* __restrict__ mats, const float* __restrict__ bbox,
    const _Float16* __restrict__ w2f, const _Float16* __restrict__ w3f,
    const float* __restrict__ b2f, const float* __restrict__ b3f,
    float* __restrict__ out) {
#pragma clang fp contract(fast)
    __shared__ __align__(16) _Float16 a2s[4][64 * 32];   // per-wave A-stage (4 KB)
    __shared__ __align__(16) _Float16 h2s[4][64 * 24];   // per-wave h2 slice (3 KB)

    int tid  = threadIdx.x;
    int wv   = tid >> 6;
    int lane = tid & 63;
    int bxs  = (blockIdx.x & 7) * 128 + (blockIdx.x >> 3);  // XCD swizzle (bijective)
    int col  = bxs * 4 + wv;               // 4096 columns: (k<<6)|j
    int j  = col & 63;
    int kz = col >> 6;
    _Float16* a2b = a2s[wv];
    _Float16* h2b = h2s[wv];

    int m = lane & 15, g = lane >> 4;
    float y = vox_coord(j, bbox[1]);
    float z = vox_coord(kz, bbox[2]);
    float x = vox_coord(lane, bbox[0]);    // lane = point index in column

    half8_t w2frag = *(const half8_t*)(w2f + lane * 8);
    half8_t w3frag = *(const half8_t*)(w3f + lane * 8);
    float b2c = b2f[lane];
    floatx4 cb2 = {b2c, b2c, b2c, b2c};
    floatx4 cb3p = { b3f[g*4+0], b3f[g*4+1], b3f[g*4+2], b3f[g*4+3] };  // per-row bias
    const half2_t z2 = { (_Float16)0.0f, (_Float16)0.0f };

    // A-stage slot offsets (halves): write lane p block q -> p*32 + (q^((p>>1)&3))*8
    int wsw0 = (lane >> 1) & 3;            // write-side swizzle key
    int rsw0 = (m >> 1) & 3;               // read-side swizzle key (same key, p=T*16+m)

    float M1[16], Msq[16], S4[4];
#pragma unroll
    for (int c = 0; c < 16; c++) { M1[c] = 0.0f; Msq[c] = 0.0f; }
#pragma unroll
    for (int c = 0; c < 4; c++) S4[c] = 0.0f;

#pragma unroll 2
    for (int v = 0; v < NVIEW; v++) {
        const float* M = mats + v * 12;
        const uint4* Gp = Gh + (size_t)v * (PLANE * 4);

        // same association as reference: M0*x + (M1*y + (M2*z + M3))
        float Ku = fmaf(M[1], y, fmaf(M[2],  z, M[3]));
        float Kv = fmaf(M[5], y, fmaf(M[6],  z, M[7]));
        float Kz = fmaf(M[9], y, fmaf(M[10], z, M[11]));

        float u  = fmaf(M[0], x, Ku);
        float vv = fmaf(M[4], x, Kv);
        float zc = fmaf(M[8], x, Kz);
        float invz = __builtin_amdgcn_rcpf(zc);
        float ix = u * invz;
        float iy = vv * invz;

        float fx0 = floorf(ix), fy0 = floorf(iy);
        float fx1 = fx0 + 1.0f, fy1 = fy0 + 1.0f;
        bool inb = (ix >= 0.0f) && (ix <= (float)(WF-1)) &&
                   (iy >= 0.0f) && (iy <= (float)(HF-1)) && (zc > 0.0f);
        int cx0 = (int)fminf(fmaxf(fx0, 0.0f), (float)(WF-1));
        int cx1 = (int)fminf(fmaxf(fx1, 0.0f), (float)(WF-1));
        int cy0 = (int)fminf(fmaxf(fy0, 0.0f), (float)(HF-1));
        int cy1 = (int)fminf(fmaxf(fy1, 0.0f), (float)(HF-1));
        float wnw = (fx1 - ix) * (fy1 - iy);
        float wne = (ix - fx0) * (fy1 - iy);
        float wsw = (fx1 - ix) * (iy - fy0);
        float wse = (ix - fx0) * (iy - fy0);

        unsigned long long bal = __ballot(inb);    // bit p = point p in-bounds
        int popc = __popcll(bal);

        int t00 = cy0 * WF + cx0, t01 = cy0 * WF + cx1;
        int t10 = cy1 * WF + cx0, t11 = cy1 * WF + cx1;
        const uint4* pA = Gp + (size_t)t00 * 4;
        const uint4* pB = Gp + (size_t)t01 * 4;
        const uint4* pC = Gp + (size_t)t10 * 4;
        const uint4* pD = Gp + (size_t)t11 * 4;

        half2_t wnw2 = { (_Float16)wnw, (_Float16)wnw };   // RTNE, once per view
        half2_t wne2 = { (_Float16)wne, (_Float16)wne };
        half2_t wsw2 = { (_Float16)wsw, (_Float16)wsw };
        half2_t wse2 = { (_Float16)wse, (_Float16)wse };

        // blend all 32 channels: acc = A*wnw; fma B,C,D; relu.
        // per-channel op order identical to previous rounds -> bit-identical.
        union { uint4 u[4]; half2_t h[16]; } ca, cb, cc4, cd, acc;
#pragma unroll
        for (int q = 0; q < 4; q++) ca.u[q] = pA[q];
#pragma unroll
        for (int q = 0; q < 4; q++) cb.u[q] = pB[q];
#pragma unroll
        for (int c = 0; c < 16; c++) acc.h[c] = ca.h[c] * wnw2;
#pragma unroll
        for (int q = 0; q < 4; q++) cc4.u[q] = pC[q];
#pragma unroll
        for (int c = 0; c < 16; c++) acc.h[c] = cb.h[c] * wne2 + acc.h[c];
#pragma unroll
        for (int q = 0; q < 4; q++) cd.u[q] = pD[q];
#pragma unroll
        for (int c = 0; c < 16; c++) acc.h[c] = cc4.h[c] * wsw2 + acc.h[c];
#pragma unroll
        for (int c = 0; c < 16; c++) {
            acc.h[c] = cd.h[c] * wse2 + acc.h[c];
            acc.h[c] = __builtin_elementwise_max(acc.h[c], z2);   // relu, packed
        }

        // stage A-frags (swizzled, conflict-free); WAR vs prev view's reads is
        // safe: DS ops are in-order per wave.
#pragma unroll
        for (int q = 0; q < 4; q++)
            *(uint4*)(a2b + lane * 32 + (q ^ wsw0) * 8) = acc.u[q];
        wave_lds_sync();

        // layer 2 per tile: read A-frag, MFMA, relu+cvt into h2 [pt][ch]
#pragma unroll
        for (int T = 0; T < 4; T++) {
            half8_t a2 = *(const half8_t*)(a2b + (T*16 + m) * 32 + (g ^ rsw0) * 8);
            floatx4 c2 = __builtin_amdgcn_mfma_f32_16x16x32_f16(a2, w2frag, cb2, 0, 0, 0);
#pragma unroll
            for (int r = 0; r < 4; r++) {
                float hv = fmaxf(c2[r], 0.0f);
                h2b[(T*16 + g*4 + r) * 24 + m] = (_Float16)hv;
            }
        }
        wave_lds_sync();

        // layer 3 (operand-swapped, R7-verified): c3' = W3^T-as-A x h2-as-B
        // + bias. C^T layout: lane (m,g) reg r -> (pt = T*16+m, ch = g*4+r).
        float msr = __builtin_amdgcn_rcpf((float)popc + 1e-8f);
        unsigned int balT[4];
        balT[0] = (unsigned int)bal;
        balT[1] = (unsigned int)(bal >> 16);
        balT[2] = (unsigned int)(bal >> 32);
        balT[3] = (unsigned int)(bal >> 48);
#pragma unroll
        for (int T = 0; T < 4; T++) {
            half8_t a3 = *(const half8_t*)(h2b + (T*16 + m) * 24 + (g & 1) * 8);
            floatx4 c3 = __builtin_amdgcn_mfma_f32_16x16x32_f16(w3frag, a3, cb3p, 0, 0, 0);
            float w = ((balT[T] >> m) & 1u) ? msr : 0.0f;   // my point, once per tile
            S4[T] += w;
#pragma unroll
            for (int r = 0; r < 4; r++) {
                float val = c3[r];
                float t1 = w * val;
                M1[T*4+r]  += t1;
                Msq[T*4+r]  = fmaf(t1, val, Msq[T*4+r]);
            }
        }
    }

    // epilogue: lane (m, g<2) owns pts T*16+m, out-chs g*4+r.
    // mean plane ch, var plane ch+8; lanes m=0..15 write 64 B bursts.
    if (g < 2) {
        size_t base = (size_t)col * 64;
#pragma unroll
        for (int T = 0; T < 4; T++) {
#pragma unroll
            for (int r = 0; r < 4; r++) {
                float mn = M1[T*4+r];
                float vr = fmaf(mn*mn, S4[T] - 2.0f, Msq[T*4+r]);
                size_t ob = base + T*16 + m;
                out[(size_t)(g*4 + r)     * 262144 + ob] = mn;
                out[(size_t)(g*4 + r + 8) * 262144 + ob] = vr;
            }
        }
    }
}

// ---- launch ----
extern "C" void kernel_launch(void* const* d_in, const int* in_sizes, int n_in,
                              void* d_out, int out_size, void* d_ws, size_t ws_size,
                              hipStream_t stream) {
    const float* feats = (const float*)d_in[0];
    const float* poses = (const float*)d_in[1];
    const float* Ks    = (const float*)d_in[2];
    const float* bbox  = (const float*)d_in[3];
    const int*   img_h = (const int*)d_in[4];
    const int*   img_w = (const int*)d_in[5];
    const float* W1    = (const float*)d_in[6];
    const float* b1    = (const float*)d_in[7];
    const float* W2    = (const float*)d_in[8];
    const float* b2    = (const float*)d_in[9];
    const float* W3    = (const float*)d_in[10];
    const float* b3    = (const float*)d_in[11];
    float* out = (float*)d_out;
    float* ws  = (float*)d_ws;

    float*     mats = ws;                        // 96 floats (pad to 128)
    _Float16*  w2f  = (_Float16*)(ws + 128);     // 512 halves (256 floats)
    _Float16*  w3f  = (_Float16*)(ws + 384);     // 512 halves
    float*     b2f  = ws + 640;                  // 64
    float*     b3f  = ws + 704;                  // 64
    uint4*     Gh   = (uint4*)(ws + 768);        // 8*16384*64 B = 8.39 MB, 16B-aligned

    hipLaunchKernelGGL(k_g, dim3(513), dim3(256), 0, stream,
                       feats, W1, b1, Gh, Ks, poses, img_h, img_w,
                       W2, b2, W3, b3, mats, w2f, w3f, b2f, b3f);
    hipLaunchKernelGGL(k_main, dim3(1024), dim3(256), 0, stream,
                       Gh, mats, bbox, w2f, w3f, b2f, b3f, out);
}